// Round 1
// baseline (400.837 us; speedup 1.0000x reference)
//
#include <hip/hip_runtime.h>
#include <hip/hip_bf16.h>
#include <math.h>

// Problem constants
#define B 16
#define T 512
#define D 256
#define H 4
#define HD 64
#define MAXREL 30
#define NREL 61          // 2*MAXREL+1
#define M_ROWS (B*T)     // 8192

// ---------------------------------------------------------------------------
// LayerNorm: one wave (64 lanes) per row of 256, float4 per lane.
// ---------------------------------------------------------------------------
__global__ __launch_bounds__(256) void ln_kernel(const float* __restrict__ x,
                                                 const float* __restrict__ gamma,
                                                 const float* __restrict__ beta,
                                                 float* __restrict__ out) {
    int row = blockIdx.x * 4 + (threadIdx.x >> 6);
    int lane = threadIdx.x & 63;
    const float* xr = x + (size_t)row * D;
    float4 v = *(const float4*)(xr + lane * 4);
    float s = v.x + v.y + v.z + v.w;
    #pragma unroll
    for (int off = 32; off; off >>= 1) s += __shfl_xor(s, off);
    float mu = s * (1.f / 256.f);
    float dx = v.x - mu, dy = v.y - mu, dz = v.z - mu, dw = v.w - mu;
    float vs = dx*dx + dy*dy + dz*dz + dw*dw;
    #pragma unroll
    for (int off = 32; off; off >>= 1) vs += __shfl_xor(vs, off);
    float rstd = rsqrtf(vs * (1.f / 256.f) + 1e-5f);
    float4 g = *(const float4*)(gamma + lane * 4);
    float4 bb = *(const float4*)(beta + lane * 4);
    float4 o;
    o.x = dx * rstd * g.x + bb.x;
    o.y = dy * rstd * g.y + bb.y;
    o.z = dz * rstd * g.z + bb.z;
    o.w = dw * rstd * g.w + bb.w;
    *(float4*)(out + (size_t)row * D + lane * 4) = o;
}

// ---------------------------------------------------------------------------
// C[M,256] = A[M,256] @ W[256,256]^T + bias.  (NT layout: C[i][j]=dot(A[i],W[j]))
// 64x64 tile, BK=64, 256 threads, 4x4 outputs/thread.
// ---------------------------------------------------------------------------
__global__ __launch_bounds__(256) void gemm_xwt(const float* __restrict__ A,
                                                const float* __restrict__ W,
                                                const float* __restrict__ bias,
                                                float* __restrict__ C, int M) {
    __shared__ float Ast[64][68];   // [k][i]
    __shared__ float Wst[64][68];   // [k][j]
    int tid = threadIdx.x;
    int i0 = blockIdx.x * 64;
    int j0 = blockIdx.y * 64;
    int tr = tid >> 4, tc = tid & 15;
    int lr = tid >> 2;             // 0..63 tile row
    int lk = (tid & 3) * 16;       // k sub-offset
    float acc[4][4] = {};
    for (int kb = 0; kb < 4; ++kb) {
        int k0 = kb * 64;
        const float* Ap = A + (size_t)(i0 + lr) * D + k0 + lk;
        const float* Wp = W + (size_t)(j0 + lr) * D + k0 + lk;
        #pragma unroll
        for (int c = 0; c < 4; ++c) {
            float4 a4 = *(const float4*)(Ap + 4 * c);
            float4 w4 = *(const float4*)(Wp + 4 * c);
            Ast[lk + 4*c + 0][lr] = a4.x; Ast[lk + 4*c + 1][lr] = a4.y;
            Ast[lk + 4*c + 2][lr] = a4.z; Ast[lk + 4*c + 3][lr] = a4.w;
            Wst[lk + 4*c + 0][lr] = w4.x; Wst[lk + 4*c + 1][lr] = w4.y;
            Wst[lk + 4*c + 2][lr] = w4.z; Wst[lk + 4*c + 3][lr] = w4.w;
        }
        __syncthreads();
        #pragma unroll 16
        for (int kk = 0; kk < 64; ++kk) {
            float4 a = *(const float4*)&Ast[kk][tr * 4];
            float4 w = *(const float4*)&Wst[kk][tc * 4];
            acc[0][0] += a.x * w.x; acc[0][1] += a.x * w.y; acc[0][2] += a.x * w.z; acc[0][3] += a.x * w.w;
            acc[1][0] += a.y * w.x; acc[1][1] += a.y * w.y; acc[1][2] += a.y * w.z; acc[1][3] += a.y * w.w;
            acc[2][0] += a.z * w.x; acc[2][1] += a.z * w.y; acc[2][2] += a.z * w.z; acc[2][3] += a.z * w.w;
            acc[3][0] += a.w * w.x; acc[3][1] += a.w * w.y; acc[3][2] += a.w * w.z; acc[3][3] += a.w * w.w;
        }
        __syncthreads();
    }
    float4 bj = *(const float4*)(bias + j0 + tc * 4);
    #pragma unroll
    for (int ii = 0; ii < 4; ++ii) {
        float4 o;
        o.x = acc[ii][0] + bj.x; o.y = acc[ii][1] + bj.y;
        o.z = acc[ii][2] + bj.z; o.w = acc[ii][3] + bj.w;
        *(float4*)(C + (size_t)(i0 + tr * 4 + ii) * D + j0 + tc * 4) = o;
    }
}

// ---------------------------------------------------------------------------
// posp[61][256] = sinusoid_enc(rel) @ Wpos^T + bpos. One block per rel pos.
// ---------------------------------------------------------------------------
__global__ __launch_bounds__(256) void pos_kernel(const float* __restrict__ Wpos,
                                                  const float* __restrict__ bpos,
                                                  float* __restrict__ posp) {
    __shared__ float enc[256];
    int p = blockIdx.x;            // 0..60  (relative distance p-30)
    int tid = threadIdx.x;
    int i = tid >> 1;
    // div_term_i = exp(-(2i) * ln(10000)/256)
    float dt = expf(-(2.f * i) * (9.210340371976184f / 256.f));
    float ang = (float)p * dt;
    enc[tid] = (tid & 1) ? cosf(ang) : sinf(ang);
    __syncthreads();
    float acc = bpos[tid];
    const float* wr = Wpos + (size_t)tid * D;
    #pragma unroll 8
    for (int k2 = 0; k2 < 256; ++k2) acc += enc[k2] * wr[k2];
    posp[p * D + tid] = acc;
}

// ---------------------------------------------------------------------------
// Attention: block = (b,h, 16-query tile). scores[16][512] in LDS, 2-pass.
// ---------------------------------------------------------------------------
#define TQ 16
__global__ __launch_bounds__(256) void attn_kernel(const float* __restrict__ q,
                                                   const float* __restrict__ k,
                                                   const float* __restrict__ v,
                                                   const float* __restrict__ posp,
                                                   const float* __restrict__ u_bias,
                                                   const float* __restrict__ v_bias,
                                                   float* __restrict__ ctx) {
    __shared__ float sc[TQ][512];     // 32 KB
    __shared__ float kv[64][65];      // 16.6 KB (k tile / v tile / posp staging)
    __shared__ float qu[TQ][64];      // q + u_bias
    __shared__ float qvb[TQ][64];     // q + v_bias
    __shared__ float pd[TQ][64];      // pdot (61 used)
    __shared__ float rinv[TQ];

    int tid = threadIdx.x;
    int bh = blockIdx.y;
    int b = bh >> 2, h = bh & 3;
    int t0 = blockIdx.x * TQ;
    const size_t baseBH = ((size_t)b * T) * D + h * HD;

    // load q rows, apply u/v biases
    for (int i = tid; i < TQ * 64; i += 256) {
        int r = i >> 6, d = i & 63;
        float qq = q[baseBH + (size_t)(t0 + r) * D + d];
        qu[r][d]  = qq + u_bias[h * HD + d];
        qvb[r][d] = qq + v_bias[h * HD + d];
    }
    // stage posp rows for this head into kv
    for (int i = tid; i < NREL * 64; i += 256) {
        int rel = i >> 6, d = i & 63;
        kv[rel][d] = posp[rel * D + h * HD + d];
    }
    __syncthreads();
    // pdot[r][rel] = dot(q[r]+v_bias, posp[rel,h])
    for (int i = tid; i < TQ * NREL; i += 256) {
        int r = i / NREL, rel = i % NREL;
        float acc = 0.f;
        #pragma unroll 16
        for (int d = 0; d < 64; ++d) acc += qvb[r][d] * kv[rel][d];
        pd[r][rel] = acc;
    }
    __syncthreads();

    int sl = tid & 63, rb = tid >> 6;    // lane-s, wave-row-base

    // -------- scores --------
    for (int st = 0; st < 8; ++st) {
        int s0 = st * 64;
        for (int i = tid; i < 64 * 64; i += 256) {
            int ss = i >> 6, d = i & 63;
            kv[ss][d] = k[baseBH + (size_t)(s0 + ss) * D + d];
        }
        __syncthreads();
        float a0 = 0.f, a1 = 0.f, a2 = 0.f, a3 = 0.f;
        #pragma unroll 16
        for (int d = 0; d < 64; ++d) {
            float kvv = kv[sl][d];
            a0 += qu[rb][d]      * kvv;
            a1 += qu[rb + 4][d]  * kvv;
            a2 += qu[rb + 8][d]  * kvv;
            a3 += qu[rb + 12][d] * kvv;
        }
        int s = s0 + sl;
        #pragma unroll
        for (int p = 0; p < 4; ++p) {
            int r = rb + p * 4;
            float accp = (p == 0) ? a0 : (p == 1) ? a1 : (p == 2) ? a2 : a3;
            int rel = s - (t0 + r);
            rel = rel < -MAXREL ? -MAXREL : (rel > MAXREL ? MAXREL : rel);
            sc[r][s] = (accp + pd[r][rel + MAXREL]) * 0.125f;
        }
        __syncthreads();
    }

    // -------- softmax (each wave: rows rb, rb+4, rb+8, rb+12) --------
    #pragma unroll
    for (int p = 0; p < 4; ++p) {
        int r = rb + p * 4;
        float vals[8];
        float m = -1e30f;
        #pragma unroll
        for (int i2 = 0; i2 < 8; ++i2) { vals[i2] = sc[r][sl + 64 * i2]; m = fmaxf(m, vals[i2]); }
        #pragma unroll
        for (int off = 32; off; off >>= 1) m = fmaxf(m, __shfl_xor(m, off));
        float ssum = 0.f;
        #pragma unroll
        for (int i2 = 0; i2 < 8; ++i2) { vals[i2] = __expf(vals[i2] - m); ssum += vals[i2]; }
        #pragma unroll
        for (int off = 32; off; off >>= 1) ssum += __shfl_xor(ssum, off);
        #pragma unroll
        for (int i2 = 0; i2 < 8; ++i2) sc[r][sl + 64 * i2] = vals[i2];
        if (sl == 0) rinv[r] = 1.f / ssum;
    }
    __syncthreads();

    // -------- PV --------
    int d = sl;
    float c0 = 0.f, c1 = 0.f, c2 = 0.f, c3 = 0.f;
    for (int st = 0; st < 8; ++st) {
        int s0 = st * 64;
        for (int i = tid; i < 64 * 64; i += 256) {
            int ss = i >> 6, dd = i & 63;
            kv[ss][dd] = v[baseBH + (size_t)(s0 + ss) * D + dd];
        }
        __syncthreads();
        #pragma unroll 16
        for (int ss = 0; ss < 64; ++ss) {
            float vv = kv[ss][d];
            int s = s0 + ss;
            c0 += sc[rb][s]      * vv;
            c1 += sc[rb + 4][s]  * vv;
            c2 += sc[rb + 8][s]  * vv;
            c3 += sc[rb + 12][s] * vv;
        }
        __syncthreads();
    }
    ctx[baseBH + (size_t)(t0 + rb)      * D + d] = c0 * rinv[rb];
    ctx[baseBH + (size_t)(t0 + rb + 4)  * D + d] = c1 * rinv[rb + 4];
    ctx[baseBH + (size_t)(t0 + rb + 8)  * D + d] = c2 * rinv[rb + 8];
    ctx[baseBH + (size_t)(t0 + rb + 12) * D + d] = c3 * rinv[rb + 12];
}

// ---------------------------------------------------------------------------
extern "C" void kernel_launch(void* const* d_in, const int* in_sizes, int n_in,
                              void* d_out, int out_size, void* d_ws, size_t ws_size,
                              hipStream_t stream) {
    const float* inputs  = (const float*)d_in[0];
    const float* ln_g    = (const float*)d_in[1];
    const float* ln_b    = (const float*)d_in[2];
    const float* Wq      = (const float*)d_in[3];
    const float* bq      = (const float*)d_in[4];
    const float* Wk      = (const float*)d_in[5];
    const float* bk      = (const float*)d_in[6];
    const float* Wv      = (const float*)d_in[7];
    const float* bv      = (const float*)d_in[8];
    const float* Wpos    = (const float*)d_in[9];
    const float* bpos    = (const float*)d_in[10];
    const float* Wo      = (const float*)d_in[11];
    const float* bo      = (const float*)d_in[12];
    const float* u_bias  = (const float*)d_in[13];
    const float* v_bias  = (const float*)d_in[14];
    float* out = (float*)d_out;

    float* ws   = (float*)d_ws;
    float* xln  = ws;                         // 8192*256
    float* q    = xln  + (size_t)M_ROWS * D;  // 8192*256
    float* k    = q    + (size_t)M_ROWS * D;
    float* v    = k    + (size_t)M_ROWS * D;
    float* ctx  = v    + (size_t)M_ROWS * D;
    float* posp = ctx  + (size_t)M_ROWS * D;  // 61*256

    ln_kernel<<<M_ROWS / 4, 256, 0, stream>>>(inputs, ln_g, ln_b, xln);

    dim3 ggrid(M_ROWS / 64, D / 64);
    gemm_xwt<<<ggrid, 256, 0, stream>>>(xln, Wq, bq, q, M_ROWS);
    gemm_xwt<<<ggrid, 256, 0, stream>>>(xln, Wk, bk, k, M_ROWS);
    gemm_xwt<<<ggrid, 256, 0, stream>>>(xln, Wv, bv, v, M_ROWS);

    pos_kernel<<<NREL, 256, 0, stream>>>(Wpos, bpos, posp);

    dim3 agrid(T / TQ, B * H);
    attn_kernel<<<agrid, 256, 0, stream>>>(q, k, v, posp, u_bias, v_bias, ctx);

    gemm_xwt<<<ggrid, 256, 0, stream>>>(ctx, Wo, bo, out, M_ROWS);
}

// Round 2
// 125.364 us; speedup vs baseline: 3.1974x; 3.1974x over previous
//
#include <hip/hip_runtime.h>
#include <hip/hip_bf16.h>
#include <math.h>

#define B 16
#define T 512
#define D 256
#define H 4
#define HD 64
#define MAXREL 30
#define NREL 61
#define M_ROWS (B*T)     // 8192
#define QBLK 64

typedef __attribute__((ext_vector_type(8))) short bf16x8;
typedef __attribute__((ext_vector_type(4))) float f32x4;

__device__ inline unsigned short f2b(float f) {
    __hip_bfloat16 h = __float2bfloat16(f);
    union { __hip_bfloat16 h; unsigned short u; } c; c.h = h; return c.u;
}
__device__ inline float b2f(unsigned short u) {
    union { unsigned short u; __hip_bfloat16 h; } c; c.u = u; return __bfloat162float(c.h);
}
// swizzled byte offset inside a [rows][64] bf16 tile (128B rows)
__device__ inline int swz(int row, int byteoff) {
    return row * 128 + (byteoff ^ ((row & 7) << 4));
}

// ---------------------------------------------------------------------------
// LayerNorm: one wave per row of 256.
// ---------------------------------------------------------------------------
__global__ __launch_bounds__(256) void ln_kernel(const float* __restrict__ x,
                                                 const float* __restrict__ gamma,
                                                 const float* __restrict__ beta,
                                                 float* __restrict__ out) {
    int row = blockIdx.x * 4 + (threadIdx.x >> 6);
    int lane = threadIdx.x & 63;
    const float* xr = x + (size_t)row * D;
    float4 v = *(const float4*)(xr + lane * 4);
    float s = v.x + v.y + v.z + v.w;
    #pragma unroll
    for (int off = 32; off; off >>= 1) s += __shfl_xor(s, off);
    float mu = s * (1.f / 256.f);
    float dx = v.x - mu, dy = v.y - mu, dz = v.z - mu, dw = v.w - mu;
    float vs = dx*dx + dy*dy + dz*dz + dw*dw;
    #pragma unroll
    for (int off = 32; off; off >>= 1) vs += __shfl_xor(vs, off);
    float rstd = rsqrtf(vs * (1.f / 256.f) + 1e-5f);
    float4 g = *(const float4*)(gamma + lane * 4);
    float4 bb = *(const float4*)(beta + lane * 4);
    float4 o;
    o.x = dx * rstd * g.x + bb.x;
    o.y = dy * rstd * g.y + bb.y;
    o.z = dz * rstd * g.z + bb.z;
    o.w = dw * rstd * g.w + bb.w;
    *(float4*)(out + (size_t)row * D + lane * 4) = o;
}

// ---------------------------------------------------------------------------
// Shared fp32 GEMM core: C[i][j] = dot(A row i, W row j). 64x64 tile, BK=64.
// Stores fp32 (out-proj), bf16 (q/k), or bf16-transposed (vT) per variant.
// ---------------------------------------------------------------------------
#define GEMM_CORE \
    __shared__ float Ast[64][68]; \
    __shared__ float Wst[64][68]; \
    int tid = threadIdx.x; \
    int i0 = blockIdx.x * 64; \
    int j0 = blockIdx.y * 64; \
    int tr = tid >> 4, tc = tid & 15; \
    int lr = tid >> 2; \
    int lk = (tid & 3) * 16; \
    float acc[4][4] = {}; \
    for (int kb = 0; kb < 4; ++kb) { \
        int k0 = kb * 64; \
        const float* Ap = A + (size_t)(i0 + lr) * D + k0 + lk; \
        const float* Wp = W + (size_t)(j0 + lr) * D + k0 + lk; \
        _Pragma("unroll") \
        for (int c = 0; c < 4; ++c) { \
            float4 a4 = *(const float4*)(Ap + 4 * c); \
            float4 w4 = *(const float4*)(Wp + 4 * c); \
            Ast[lk + 4*c + 0][lr] = a4.x; Ast[lk + 4*c + 1][lr] = a4.y; \
            Ast[lk + 4*c + 2][lr] = a4.z; Ast[lk + 4*c + 3][lr] = a4.w; \
            Wst[lk + 4*c + 0][lr] = w4.x; Wst[lk + 4*c + 1][lr] = w4.y; \
            Wst[lk + 4*c + 2][lr] = w4.z; Wst[lk + 4*c + 3][lr] = w4.w; \
        } \
        __syncthreads(); \
        _Pragma("unroll 16") \
        for (int kk = 0; kk < 64; ++kk) { \
            float4 a = *(const float4*)&Ast[kk][tr * 4]; \
            float4 w = *(const float4*)&Wst[kk][tc * 4]; \
            acc[0][0] += a.x * w.x; acc[0][1] += a.x * w.y; acc[0][2] += a.x * w.z; acc[0][3] += a.x * w.w; \
            acc[1][0] += a.y * w.x; acc[1][1] += a.y * w.y; acc[1][2] += a.y * w.z; acc[1][3] += a.y * w.w; \
            acc[2][0] += a.z * w.x; acc[2][1] += a.z * w.y; acc[2][2] += a.z * w.z; acc[2][3] += a.z * w.w; \
            acc[3][0] += a.w * w.x; acc[3][1] += a.w * w.y; acc[3][2] += a.w * w.z; acc[3][3] += a.w * w.w; \
        } \
        __syncthreads(); \
    }

__global__ __launch_bounds__(256) void gemm_xwt(const float* __restrict__ A,
                                                const float* __restrict__ W,
                                                const float* __restrict__ bias,
                                                float* __restrict__ C) {
    GEMM_CORE
    float4 bj = *(const float4*)(bias + j0 + tc * 4);
    #pragma unroll
    for (int ii = 0; ii < 4; ++ii) {
        float4 o;
        o.x = acc[ii][0] + bj.x; o.y = acc[ii][1] + bj.y;
        o.z = acc[ii][2] + bj.z; o.w = acc[ii][3] + bj.w;
        *(float4*)(C + (size_t)(i0 + tr * 4 + ii) * D + j0 + tc * 4) = o;
    }
}

__global__ __launch_bounds__(256) void gemm_xwt_bf16(const float* __restrict__ A,
                                                     const float* __restrict__ W,
                                                     const float* __restrict__ bias,
                                                     unsigned short* __restrict__ Cb) {
    GEMM_CORE
    float4 bj = *(const float4*)(bias + j0 + tc * 4);
    #pragma unroll
    for (int ii = 0; ii < 4; ++ii) {
        ushort4 o;
        o.x = f2b(acc[ii][0] + bj.x); o.y = f2b(acc[ii][1] + bj.y);
        o.z = f2b(acc[ii][2] + bj.z); o.w = f2b(acc[ii][3] + bj.w);
        *(ushort4*)(Cb + (size_t)(i0 + tr * 4 + ii) * D + j0 + tc * 4) = o;
    }
}

// transposed bf16 output: Ct[j][i], j = feature (h*64+d), i = token. Row stride M_ROWS.
__global__ __launch_bounds__(256) void gemm_xwt_T_bf16(const float* __restrict__ A,
                                                       const float* __restrict__ W,
                                                       const float* __restrict__ bias,
                                                       unsigned short* __restrict__ Ct) {
    GEMM_CORE
    float4 bj = *(const float4*)(bias + j0 + tc * 4);
    float bjv[4] = {bj.x, bj.y, bj.z, bj.w};
    #pragma unroll
    for (int jj = 0; jj < 4; ++jj) {
        ushort4 o;
        o.x = f2b(acc[0][jj] + bjv[jj]);
        o.y = f2b(acc[1][jj] + bjv[jj]);
        o.z = f2b(acc[2][jj] + bjv[jj]);
        o.w = f2b(acc[3][jj] + bjv[jj]);
        *(ushort4*)(Ct + (size_t)(j0 + tc * 4 + jj) * M_ROWS + i0 + tr * 4) = o;
    }
}

// ---------------------------------------------------------------------------
// posp[61][256] = sinusoid_enc @ Wpos^T + bpos (fp32)
// ---------------------------------------------------------------------------
__global__ __launch_bounds__(256) void pos_kernel(const float* __restrict__ Wpos,
                                                  const float* __restrict__ bpos,
                                                  float* __restrict__ posp) {
    __shared__ float enc[256];
    int p = blockIdx.x;
    int tid = threadIdx.x;
    int i = tid >> 1;
    float dt = expf(-(2.f * i) * (9.210340371976184f / 256.f));
    float ang = (float)p * dt;
    enc[tid] = (tid & 1) ? cosf(ang) : sinf(ang);
    __syncthreads();
    float acc = bpos[tid];
    const float* wr = Wpos + (size_t)tid * D;
    #pragma unroll 8
    for (int k2 = 0; k2 < 256; ++k2) acc += enc[k2] * wr[k2];
    posp[p * D + tid] = acc;
}

// ---------------------------------------------------------------------------
// Flash-style MFMA attention. Block = (b,h) x 64-query tile, 4 waves x 16 rows.
// ---------------------------------------------------------------------------
__global__ __launch_bounds__(256, 2) void attn_mfma(const unsigned short* __restrict__ qb,
                                                    const unsigned short* __restrict__ kb,
                                                    const unsigned short* __restrict__ vtb,
                                                    const float* __restrict__ posp,
                                                    const float* __restrict__ u_bias,
                                                    const float* __restrict__ v_bias,
                                                    float* __restrict__ ctx) {
    __shared__ __attribute__((aligned(16))) unsigned short QuS[64 * 64];
    __shared__ __attribute__((aligned(16))) unsigned short QvS[64 * 64];
    __shared__ __attribute__((aligned(16))) unsigned short KbS[64 * 64];  // posp staging, then K tiles
    __shared__ __attribute__((aligned(16))) unsigned short VtS[64 * 64];
    __shared__ __attribute__((aligned(16))) float pdS[64 * 64];           // [t_loc][rel]
    __shared__ __attribute__((aligned(16))) unsigned short PlS[4][16 * 64];

    int tid = threadIdx.x;
    int w = tid >> 6;          // wave 0..3
    int l = tid & 63;          // lane
    int bh = blockIdx.y;
    int b = bh >> 2, h = bh & 3;
    int t0 = blockIdx.x * QBLK;
    const size_t baseBH = ((size_t)b * T) * D + h * HD;

    // ---- stage Qu = q+u_bias, Qv = q+v_bias (bf16, swizzled) ----
    {
        const unsigned short* qsrc = qb + baseBH + (size_t)t0 * D;
        #pragma unroll
        for (int c = 0; c < 2; ++c) {
            int idx = tid + c * 256;
            int r = idx >> 3, d8 = (idx & 7) * 8;
            bf16x8 ld = *(const bf16x8*)(qsrc + (size_t)r * D + d8);
            const float* ub = u_bias + h * HD + d8;
            const float* vb = v_bias + h * HD + d8;
            bf16x8 ou, ov;
            #pragma unroll
            for (int j = 0; j < 8; ++j) {
                float f = b2f((unsigned short)ld[j]);
                ou[j] = (short)f2b(f + ub[j]);
                ov[j] = (short)f2b(f + vb[j]);
            }
            *(bf16x8*)((char*)QuS + swz(r, d8 * 2)) = ou;
            *(bf16x8*)((char*)QvS + swz(r, d8 * 2)) = ov;
        }
    }
    // ---- stage posp head-slice into KbS (rows 61..63 zero) ----
    {
        #pragma unroll
        for (int c = 0; c < 4; ++c) {
            int idx = tid + c * 256;
            int r = idx >> 4, d4 = (idx & 15) * 4;
            float4 pv = make_float4(0.f, 0.f, 0.f, 0.f);
            if (r < NREL) pv = *(const float4*)(posp + (size_t)r * D + h * HD + d4);
            ushort4 o;
            o.x = f2b(pv.x); o.y = f2b(pv.y); o.z = f2b(pv.z); o.w = f2b(pv.w);
            *(ushort4*)((char*)KbS + swz(r, d4 * 2)) = o;
        }
    }
    __syncthreads();

    // ---- pd[t][rel] = (q+v_bias) . posp_h  via MFMA ----
    {
        f32x4 pacc[4] = {};
        #pragma unroll
        for (int ks = 0; ks < 2; ++ks) {
            int koff = ks * 32 + 8 * (l >> 4);
            bf16x8 a = *(const bf16x8*)((const char*)QvS + swz(w * 16 + (l & 15), koff * 2));
            #pragma unroll
            for (int ct = 0; ct < 4; ++ct) {
                bf16x8 bf = *(const bf16x8*)((const char*)KbS + swz(ct * 16 + (l & 15), koff * 2));
                pacc[ct] = __builtin_amdgcn_mfma_f32_16x16x32_bf16(a, bf, pacc[ct], 0, 0, 0);
            }
        }
        #pragma unroll
        for (int ct = 0; ct < 4; ++ct)
            #pragma unroll
            for (int r = 0; r < 4; ++r)
                pdS[(w * 16 + (l >> 4) * 4 + r) * 64 + ct * 16 + (l & 15)] = pacc[ct][r];
    }

    // ---- flash main loop over 8 KV tiles ----
    float m_run[4] = {-1e30f, -1e30f, -1e30f, -1e30f};
    float l_run[4] = {};
    f32x4 o_acc[4] = {};

    for (int st = 0; st < 8; ++st) {
        int s0 = st * 64;
        __syncthreads();
        // stage K tile (row-major) and V^T tile (rows=d, cols=s)
        {
            const unsigned short* ksrc = kb + baseBH + (size_t)s0 * D;
            const unsigned short* vsrc = vtb + (size_t)(h * HD) * M_ROWS + (size_t)b * T + s0;
            #pragma unroll
            for (int c = 0; c < 2; ++c) {
                int idx = tid + c * 256;
                int r = idx >> 3, d8 = (idx & 7) * 8;
                bf16x8 lk = *(const bf16x8*)(ksrc + (size_t)r * D + d8);
                *(bf16x8*)((char*)KbS + swz(r, d8 * 2)) = lk;
                bf16x8 lv = *(const bf16x8*)(vsrc + (size_t)r * M_ROWS + d8);
                *(bf16x8*)((char*)VtS + swz(r, d8 * 2)) = lv;
            }
        }
        __syncthreads();

        // QK^T
        f32x4 sacc[4] = {};
        #pragma unroll
        for (int ks = 0; ks < 2; ++ks) {
            int koff = ks * 32 + 8 * (l >> 4);
            bf16x8 a = *(const bf16x8*)((const char*)QuS + swz(w * 16 + (l & 15), koff * 2));
            #pragma unroll
            for (int ct = 0; ct < 4; ++ct) {
                bf16x8 bf = *(const bf16x8*)((const char*)KbS + swz(ct * 16 + (l & 15), koff * 2));
                sacc[ct] = __builtin_amdgcn_mfma_f32_16x16x32_bf16(a, bf, sacc[ct], 0, 0, 0);
            }
        }

        // pos add + scale
        #pragma unroll
        for (int ct = 0; ct < 4; ++ct) {
            int s_g = s0 + ct * 16 + (l & 15);
            #pragma unroll
            for (int r = 0; r < 4; ++r) {
                int t_loc = w * 16 + (l >> 4) * 4 + r;
                int rel = s_g - (t0 + t_loc);
                rel = rel < -MAXREL ? -MAXREL : (rel > MAXREL ? MAXREL : rel);
                sacc[ct][r] = (sacc[ct][r] + pdS[t_loc * 64 + rel + MAXREL]) * 0.125f;
            }
        }

        // online softmax (rows live in 16-lane groups; shfl_xor 1,2,4,8)
        #pragma unroll
        for (int r = 0; r < 4; ++r) {
            float mt = fmaxf(fmaxf(sacc[0][r], sacc[1][r]), fmaxf(sacc[2][r], sacc[3][r]));
            #pragma unroll
            for (int off = 8; off; off >>= 1) mt = fmaxf(mt, __shfl_xor(mt, off));
            float mn = fmaxf(m_run[r], mt);
            float al = __expf(m_run[r] - mn);
            m_run[r] = mn;
            float rs = 0.f;
            #pragma unroll
            for (int ct = 0; ct < 4; ++ct) {
                float p = __expf(sacc[ct][r] - mn);
                sacc[ct][r] = p;
                rs += p;
            }
            #pragma unroll
            for (int off = 8; off; off >>= 1) rs += __shfl_xor(rs, off);
            l_run[r] = l_run[r] * al + rs;
            #pragma unroll
            for (int cd = 0; cd < 4; ++cd) o_acc[cd][r] *= al;
        }

        // write P (bf16, swizzled) into per-wave LDS
        unsigned short* pw = PlS[w];
        #pragma unroll
        for (int ct = 0; ct < 4; ++ct)
            #pragma unroll
            for (int r = 0; r < 4; ++r) {
                int row = (l >> 4) * 4 + r;
                int col = ct * 16 + (l & 15);
                *(unsigned short*)((char*)pw + swz(row, col * 2)) = f2b(sacc[ct][r]);
            }

        // PV
        #pragma unroll
        for (int ks = 0; ks < 2; ++ks) {
            int koff = ks * 32 + 8 * (l >> 4);
            bf16x8 a = *(const bf16x8*)((const char*)pw + swz(l & 15, koff * 2));
            #pragma unroll
            for (int cd = 0; cd < 4; ++cd) {
                bf16x8 bv8 = *(const bf16x8*)((const char*)VtS + swz(cd * 16 + (l & 15), koff * 2));
                o_acc[cd] = __builtin_amdgcn_mfma_f32_16x16x32_bf16(a, bv8, o_acc[cd], 0, 0, 0);
            }
        }
    }

    // ---- normalize + write ctx (fp32, [b][t][h*64+d]) ----
    float inv[4];
    #pragma unroll
    for (int r = 0; r < 4; ++r) inv[r] = 1.f / l_run[r];
    #pragma unroll
    for (int cd = 0; cd < 4; ++cd)
        #pragma unroll
        for (int r = 0; r < 4; ++r) {
            int t_loc = w * 16 + (l >> 4) * 4 + r;
            ctx[baseBH + (size_t)(t0 + t_loc) * D + cd * 16 + (l & 15)] = o_acc[cd][r] * inv[r];
        }
}

// ---------------------------------------------------------------------------
extern "C" void kernel_launch(void* const* d_in, const int* in_sizes, int n_in,
                              void* d_out, int out_size, void* d_ws, size_t ws_size,
                              hipStream_t stream) {
    const float* inputs  = (const float*)d_in[0];
    const float* ln_g    = (const float*)d_in[1];
    const float* ln_b    = (const float*)d_in[2];
    const float* Wq      = (const float*)d_in[3];
    const float* bq      = (const float*)d_in[4];
    const float* Wk      = (const float*)d_in[5];
    const float* bk      = (const float*)d_in[6];
    const float* Wv      = (const float*)d_in[7];
    const float* bv      = (const float*)d_in[8];
    const float* Wpos    = (const float*)d_in[9];
    const float* bpos    = (const float*)d_in[10];
    const float* Wo      = (const float*)d_in[11];
    const float* bo      = (const float*)d_in[12];
    const float* u_bias  = (const float*)d_in[13];
    const float* v_bias  = (const float*)d_in[14];
    float* out = (float*)d_out;

    char* w = (char*)d_ws;
    float* xln = (float*)w;            w += (size_t)M_ROWS * D * 4;   // 8MB
    float* ctx = (float*)w;            w += (size_t)M_ROWS * D * 4;   // 8MB
    float* posp = (float*)w;           w += (size_t)NREL * D * 4;
    unsigned short* qb = (unsigned short*)w;  w += (size_t)M_ROWS * D * 2;  // 4MB
    unsigned short* kbuf = (unsigned short*)w; w += (size_t)M_ROWS * D * 2; // 4MB
    unsigned short* vtb = (unsigned short*)w;  w += (size_t)M_ROWS * D * 2; // 4MB

    ln_kernel<<<M_ROWS / 4, 256, 0, stream>>>(inputs, ln_g, ln_b, xln);

    dim3 ggrid(M_ROWS / 64, D / 64);
    gemm_xwt_bf16<<<ggrid, 256, 0, stream>>>(xln, Wq, bq, qb);
    gemm_xwt_bf16<<<ggrid, 256, 0, stream>>>(xln, Wk, bk, kbuf);
    gemm_xwt_T_bf16<<<ggrid, 256, 0, stream>>>(xln, Wv, bv, vtb);

    pos_kernel<<<NREL, 256, 0, stream>>>(Wpos, bpos, posp);

    dim3 agrid(T / QBLK, B * H);
    attn_mfma<<<agrid, 256, 0, stream>>>(qb, kbuf, vtb, posp, u_bias, v_bias, ctx);

    gemm_xwt<<<ggrid, 256, 0, stream>>>(ctx, Wo, bo, out);
}

// Round 3
// 78.029 us; speedup vs baseline: 5.1370x; 1.6066x over previous
//
#include <hip/hip_runtime.h>
#include <hip/hip_bf16.h>
#include <math.h>

#define B 16
#define T 512
#define D 256
#define H 4
#define HD 64
#define MAXREL 30
#define NREL 61
#define M_ROWS (B*T)     // 8192
#define QBLK 64

typedef __attribute__((ext_vector_type(8))) short bf16x8;
typedef __attribute__((ext_vector_type(4))) float f32x4;
typedef unsigned short ush;

__device__ inline ush f2b(float f) {
    __hip_bfloat16 h = __float2bfloat16(f);
    union { __hip_bfloat16 h; ush u; } c; c.h = h; return c.u;
}
__device__ inline float b2f(ush u) {
    union { ush u; __hip_bfloat16 h; } c; c.u = u; return __bfloat162float(c.h);
}
// swizzled byte offset inside a [rows][64] bf16 tile (128B rows)
__device__ inline int swz(int row, int byteoff) {
    return row * 128 + (byteoff ^ ((row & 7) << 4));
}
// swizzled byte offset inside a [rows][128] bf16 tile (256B rows)
__device__ inline int swz256(int row, int byteoff) {
    return row * 256 + (byteoff ^ ((row & 7) << 4));
}

// ---------------------------------------------------------------------------
// LayerNorm: one wave per row of 256 -> bf16 out.
// ---------------------------------------------------------------------------
__global__ __launch_bounds__(256) void ln_kernel(const float* __restrict__ x,
                                                 const float* __restrict__ gamma,
                                                 const float* __restrict__ beta,
                                                 ush* __restrict__ out) {
    int row = blockIdx.x * 4 + (threadIdx.x >> 6);
    int lane = threadIdx.x & 63;
    const float* xr = x + (size_t)row * D;
    float4 v = *(const float4*)(xr + lane * 4);
    float s = v.x + v.y + v.z + v.w;
    #pragma unroll
    for (int off = 32; off; off >>= 1) s += __shfl_xor(s, off);
    float mu = s * (1.f / 256.f);
    float dx = v.x - mu, dy = v.y - mu, dz = v.z - mu, dw = v.w - mu;
    float vs = dx*dx + dy*dy + dz*dz + dw*dw;
    #pragma unroll
    for (int off = 32; off; off >>= 1) vs += __shfl_xor(vs, off);
    float rstd = rsqrtf(vs * (1.f / 256.f) + 1e-5f);
    float4 g = *(const float4*)(gamma + lane * 4);
    float4 bb = *(const float4*)(beta + lane * 4);
    ushort4 o;
    o.x = f2b(dx * rstd * g.x + bb.x);
    o.y = f2b(dy * rstd * g.y + bb.y);
    o.z = f2b(dz * rstd * g.z + bb.z);
    o.w = f2b(dw * rstd * g.w + bb.w);
    *(ushort4*)(out + (size_t)row * D + lane * 4) = o;
}

// ---------------------------------------------------------------------------
// Convert the 4 weight matrices (256x256 fp32) to bf16, concatenated.
// ---------------------------------------------------------------------------
__global__ __launch_bounds__(256) void wconv(const float* __restrict__ Wq, const float* __restrict__ Wk,
                                             const float* __restrict__ Wv, const float* __restrict__ Wo,
                                             ush* __restrict__ out) {
    int z = blockIdx.y;
    const float* src = z == 0 ? Wq : z == 1 ? Wk : z == 2 ? Wv : Wo;
    int idx = (blockIdx.x * 256 + threadIdx.x) * 4;
    float4 v = *(const float4*)(src + idx);
    ushort4 o;
    o.x = f2b(v.x); o.y = f2b(v.y); o.z = f2b(v.z); o.w = f2b(v.w);
    *(ushort4*)(out + (size_t)z * 65536 + idx) = o;
}

// ---------------------------------------------------------------------------
// posp[61][256] = sinusoid_enc @ Wpos^T + bpos (fp32)
// ---------------------------------------------------------------------------
__global__ __launch_bounds__(256) void pos_kernel(const float* __restrict__ Wpos,
                                                  const float* __restrict__ bpos,
                                                  float* __restrict__ posp) {
    __shared__ float enc[256];
    int p = blockIdx.x;
    int tid = threadIdx.x;
    int i = tid >> 1;
    float dt = expf(-(2.f * i) * (9.210340371976184f / 256.f));
    float ang = (float)p * dt;
    enc[tid] = (tid & 1) ? cosf(ang) : sinf(ang);
    __syncthreads();
    float acc = bpos[tid];
    const float* wr = Wpos + (size_t)tid * D;
    #pragma unroll 8
    for (int k2 = 0; k2 < 256; ++k2) acc += enc[k2] * wr[k2];
    posp[p * D + tid] = acc;
}

// ---------------------------------------------------------------------------
// MFMA projection GEMM: C = A[8192,256](bf16) @ W[256,256](bf16)^T + bias.
// 128x128 tile, 4 waves (2x2), BK=128, swizzled LDS.
// mode 0: bf16 row-major out (ob[t][j])      -- Q, K   (D computed as [j][t])
// mode 1: bf16 transposed out (ob[j][t])     -- V^T    (D computed as [t][j])
// mode 2: fp32 row-major out (of[t][j])      -- out-projection
// ---------------------------------------------------------------------------
__global__ __launch_bounds__(256, 2) void proj_mfma(const ush* __restrict__ A,
                                                    const ush* __restrict__ W,
                                                    const float* __restrict__ bias,
                                                    ush* __restrict__ ob,
                                                    float* __restrict__ of,
                                                    int mode) {
    __shared__ __attribute__((aligned(16))) ush A_s[128 * 128];
    __shared__ __attribute__((aligned(16))) ush B_s[128 * 128];
    int tid = threadIdx.x;
    int w = tid >> 6, l = tid & 63;
    int wr = w >> 1, wc = w & 1;
    int i0 = blockIdx.x * 128, j0 = blockIdx.y * 128;
    const ush* Ap = A + (size_t)i0 * D;
    const ush* Wp = W + (size_t)j0 * D;
    f32x4 acc[4][4] = {};

    #pragma unroll 1
    for (int kb2 = 0; kb2 < 2; ++kb2) {
        int k0 = kb2 * 128;
        if (kb2) __syncthreads();
        #pragma unroll
        for (int c = 0; c < 8; ++c) {
            int ci = c * 256 + tid;
            int row = ci >> 4, sub = ci & 15;
            bf16x8 va = *(const bf16x8*)(Ap + (size_t)row * D + k0 + sub * 8);
            *(bf16x8*)((char*)A_s + swz256(row, sub * 16)) = va;
            bf16x8 vb = *(const bf16x8*)(Wp + (size_t)row * D + k0 + sub * 8);
            *(bf16x8*)((char*)B_s + swz256(row, sub * 16)) = vb;
        }
        __syncthreads();
        const char* aSrc = (mode == 1) ? (const char*)A_s : (const char*)B_s;
        const char* bSrc = (mode == 1) ? (const char*)B_s : (const char*)A_s;
        __builtin_amdgcn_s_setprio(1);
        #pragma unroll
        for (int ksub = 0; ksub < 4; ++ksub) {
            int kbyte = ksub * 64 + (l >> 4) * 16;
            bf16x8 af[4], bfr[4];
            #pragma unroll
            for (int mi = 0; mi < 4; ++mi)
                af[mi] = *(const bf16x8*)(aSrc + swz256(wr * 64 + mi * 16 + (l & 15), kbyte));
            #pragma unroll
            for (int ni = 0; ni < 4; ++ni)
                bfr[ni] = *(const bf16x8*)(bSrc + swz256(wc * 64 + ni * 16 + (l & 15), kbyte));
            #pragma unroll
            for (int mi = 0; mi < 4; ++mi)
                #pragma unroll
                for (int ni = 0; ni < 4; ++ni)
                    acc[mi][ni] = __builtin_amdgcn_mfma_f32_16x16x32_bf16(af[mi], bfr[ni], acc[mi][ni], 0, 0, 0);
        }
        __builtin_amdgcn_s_setprio(0);
    }

    if (mode == 1) {
        // D[t][j]: quad of 4 consecutive t at fixed j -> ushort4 into ob[j][t]
        #pragma unroll
        for (int mi = 0; mi < 4; ++mi) {
            int t = i0 + wr * 64 + mi * 16 + (l >> 4) * 4;
            #pragma unroll
            for (int ni = 0; ni < 4; ++ni) {
                int j = j0 + wc * 64 + ni * 16 + (l & 15);
                float bv = bias[j];
                ushort4 o;
                o.x = f2b(acc[mi][ni][0] + bv); o.y = f2b(acc[mi][ni][1] + bv);
                o.z = f2b(acc[mi][ni][2] + bv); o.w = f2b(acc[mi][ni][3] + bv);
                *(ushort4*)(ob + (size_t)j * M_ROWS + t) = o;
            }
        }
    } else {
        // D[j][t]: quad of 4 consecutive j at fixed t -> packed store into [t][j]
        #pragma unroll
        for (int mi = 0; mi < 4; ++mi) {
            int jb = j0 + wr * 64 + mi * 16 + (l >> 4) * 4;
            float4 bv = *(const float4*)(bias + jb);
            #pragma unroll
            for (int ni = 0; ni < 4; ++ni) {
                int t = i0 + wc * 64 + ni * 16 + (l & 15);
                if (mode == 0) {
                    ushort4 o;
                    o.x = f2b(acc[mi][ni][0] + bv.x); o.y = f2b(acc[mi][ni][1] + bv.y);
                    o.z = f2b(acc[mi][ni][2] + bv.z); o.w = f2b(acc[mi][ni][3] + bv.w);
                    *(ushort4*)(ob + (size_t)t * D + jb) = o;
                } else {
                    float4 o;
                    o.x = acc[mi][ni][0] + bv.x; o.y = acc[mi][ni][1] + bv.y;
                    o.z = acc[mi][ni][2] + bv.z; o.w = acc[mi][ni][3] + bv.w;
                    *(float4*)(of + (size_t)t * D + jb) = o;
                }
            }
        }
    }
}

// ---------------------------------------------------------------------------
// Flash-style MFMA attention. Block = (b,h) x 64-query tile, 4 waves x 16 rows.
// ---------------------------------------------------------------------------
__global__ __launch_bounds__(256, 2) void attn_mfma(const ush* __restrict__ qb,
                                                    const ush* __restrict__ kb,
                                                    const ush* __restrict__ vtb,
                                                    const float* __restrict__ posp,
                                                    const float* __restrict__ u_bias,
                                                    const float* __restrict__ v_bias,
                                                    ush* __restrict__ ctxb) {
    __shared__ __attribute__((aligned(16))) ush QuS[64 * 64];
    __shared__ __attribute__((aligned(16))) ush QvS[64 * 64];
    __shared__ __attribute__((aligned(16))) ush KbS[64 * 64];  // posp staging, then K tiles
    __shared__ __attribute__((aligned(16))) ush VtS[64 * 64];
    __shared__ __attribute__((aligned(16))) float pdS[64 * 64]; // [t_loc][rel]
    __shared__ __attribute__((aligned(16))) ush PlS[4][16 * 64];

    int tid = threadIdx.x;
    int w = tid >> 6;
    int l = tid & 63;
    int bh = blockIdx.y;
    int b = bh >> 2, h = bh & 3;
    int t0 = blockIdx.x * QBLK;
    const size_t baseBH = ((size_t)b * T) * D + h * HD;

    // ---- stage Qu = q+u_bias, Qv = q+v_bias (bf16, swizzled) ----
    {
        const ush* qsrc = qb + baseBH + (size_t)t0 * D;
        #pragma unroll
        for (int c = 0; c < 2; ++c) {
            int idx = tid + c * 256;
            int r = idx >> 3, d8 = (idx & 7) * 8;
            bf16x8 ld = *(const bf16x8*)(qsrc + (size_t)r * D + d8);
            const float* ub = u_bias + h * HD + d8;
            const float* vb = v_bias + h * HD + d8;
            bf16x8 ou, ov;
            #pragma unroll
            for (int j = 0; j < 8; ++j) {
                float f = b2f((ush)ld[j]);
                ou[j] = (short)f2b(f + ub[j]);
                ov[j] = (short)f2b(f + vb[j]);
            }
            *(bf16x8*)((char*)QuS + swz(r, d8 * 2)) = ou;
            *(bf16x8*)((char*)QvS + swz(r, d8 * 2)) = ov;
        }
    }
    // ---- stage posp head-slice into KbS (rows 61..63 zero) ----
    {
        #pragma unroll
        for (int c = 0; c < 4; ++c) {
            int idx = tid + c * 256;
            int r = idx >> 4, d4 = (idx & 15) * 4;
            float4 pv = make_float4(0.f, 0.f, 0.f, 0.f);
            if (r < NREL) pv = *(const float4*)(posp + (size_t)r * D + h * HD + d4);
            ushort4 o;
            o.x = f2b(pv.x); o.y = f2b(pv.y); o.z = f2b(pv.z); o.w = f2b(pv.w);
            *(ushort4*)((char*)KbS + swz(r, d4 * 2)) = o;
        }
    }
    __syncthreads();

    // ---- pd[t][rel] = (q+v_bias) . posp_h  via MFMA ----
    {
        f32x4 pacc[4] = {};
        __builtin_amdgcn_s_setprio(1);
        #pragma unroll
        for (int ks = 0; ks < 2; ++ks) {
            int koff = ks * 32 + 8 * (l >> 4);
            bf16x8 a = *(const bf16x8*)((const char*)QvS + swz(w * 16 + (l & 15), koff * 2));
            #pragma unroll
            for (int ct = 0; ct < 4; ++ct) {
                bf16x8 bf = *(const bf16x8*)((const char*)KbS + swz(ct * 16 + (l & 15), koff * 2));
                pacc[ct] = __builtin_amdgcn_mfma_f32_16x16x32_bf16(a, bf, pacc[ct], 0, 0, 0);
            }
        }
        __builtin_amdgcn_s_setprio(0);
        #pragma unroll
        for (int ct = 0; ct < 4; ++ct)
            #pragma unroll
            for (int r = 0; r < 4; ++r)
                pdS[(w * 16 + (l >> 4) * 4 + r) * 64 + ct * 16 + (l & 15)] = pacc[ct][r];
    }

    // ---- flash main loop over 8 KV tiles ----
    float m_run[4] = {-1e30f, -1e30f, -1e30f, -1e30f};
    float l_run[4] = {};
    f32x4 o_acc[4] = {};

    for (int st = 0; st < 8; ++st) {
        int s0 = st * 64;
        __syncthreads();
        {
            const ush* ksrc = kb + baseBH + (size_t)s0 * D;
            const ush* vsrc = vtb + (size_t)(h * HD) * M_ROWS + (size_t)b * T + s0;
            #pragma unroll
            for (int c = 0; c < 2; ++c) {
                int idx = tid + c * 256;
                int r = idx >> 3, d8 = (idx & 7) * 8;
                bf16x8 lk = *(const bf16x8*)(ksrc + (size_t)r * D + d8);
                *(bf16x8*)((char*)KbS + swz(r, d8 * 2)) = lk;
                bf16x8 lv = *(const bf16x8*)(vsrc + (size_t)r * M_ROWS + d8);
                *(bf16x8*)((char*)VtS + swz(r, d8 * 2)) = lv;
            }
        }
        __syncthreads();

        // QK^T
        f32x4 sacc[4] = {};
        __builtin_amdgcn_s_setprio(1);
        #pragma unroll
        for (int ks = 0; ks < 2; ++ks) {
            int koff = ks * 32 + 8 * (l >> 4);
            bf16x8 a = *(const bf16x8*)((const char*)QuS + swz(w * 16 + (l & 15), koff * 2));
            #pragma unroll
            for (int ct = 0; ct < 4; ++ct) {
                bf16x8 bf = *(const bf16x8*)((const char*)KbS + swz(ct * 16 + (l & 15), koff * 2));
                sacc[ct] = __builtin_amdgcn_mfma_f32_16x16x32_bf16(a, bf, sacc[ct], 0, 0, 0);
            }
        }
        __builtin_amdgcn_s_setprio(0);

        // pos add + scale
        #pragma unroll
        for (int ct = 0; ct < 4; ++ct) {
            int s_g = s0 + ct * 16 + (l & 15);
            #pragma unroll
            for (int r = 0; r < 4; ++r) {
                int t_loc = w * 16 + (l >> 4) * 4 + r;
                int rel = s_g - (t0 + t_loc);
                rel = rel < -MAXREL ? -MAXREL : (rel > MAXREL ? MAXREL : rel);
                sacc[ct][r] = (sacc[ct][r] + pdS[t_loc * 64 + rel + MAXREL]) * 0.125f;
            }
        }

        // online softmax (rows live in 16-lane groups)
        #pragma unroll
        for (int r = 0; r < 4; ++r) {
            float mt = fmaxf(fmaxf(sacc[0][r], sacc[1][r]), fmaxf(sacc[2][r], sacc[3][r]));
            #pragma unroll
            for (int off = 8; off; off >>= 1) mt = fmaxf(mt, __shfl_xor(mt, off));
            float mn = fmaxf(m_run[r], mt);
            float al = __expf(m_run[r] - mn);
            m_run[r] = mn;
            float rs = 0.f;
            #pragma unroll
            for (int ct = 0; ct < 4; ++ct) {
                float p = __expf(sacc[ct][r] - mn);
                sacc[ct][r] = p;
                rs += p;
            }
            #pragma unroll
            for (int off = 8; off; off >>= 1) rs += __shfl_xor(rs, off);
            l_run[r] = l_run[r] * al + rs;
            #pragma unroll
            for (int cd = 0; cd < 4; ++cd) o_acc[cd][r] *= al;
        }

        // write P (bf16, swizzled) into per-wave LDS
        ush* pw = PlS[w];
        #pragma unroll
        for (int ct = 0; ct < 4; ++ct)
            #pragma unroll
            for (int r = 0; r < 4; ++r) {
                int row = (l >> 4) * 4 + r;
                int col = ct * 16 + (l & 15);
                *(ush*)((char*)pw + swz(row, col * 2)) = f2b(sacc[ct][r]);
            }

        // PV
        __builtin_amdgcn_s_setprio(1);
        #pragma unroll
        for (int ks = 0; ks < 2; ++ks) {
            int koff = ks * 32 + 8 * (l >> 4);
            bf16x8 a = *(const bf16x8*)((const char*)pw + swz(l & 15, koff * 2));
            #pragma unroll
            for (int cd = 0; cd < 4; ++cd) {
                bf16x8 bv8 = *(const bf16x8*)((const char*)VtS + swz(cd * 16 + (l & 15), koff * 2));
                o_acc[cd] = __builtin_amdgcn_mfma_f32_16x16x32_bf16(a, bv8, o_acc[cd], 0, 0, 0);
            }
        }
        __builtin_amdgcn_s_setprio(0);
    }

    // ---- normalize + write ctx (bf16 row-major) ----
    float inv[4];
    #pragma unroll
    for (int r = 0; r < 4; ++r) inv[r] = 1.f / l_run[r];
    #pragma unroll
    for (int cd = 0; cd < 4; ++cd)
        #pragma unroll
        for (int r = 0; r < 4; ++r) {
            int t_loc = w * 16 + (l >> 4) * 4 + r;
            ctxb[baseBH + (size_t)(t0 + t_loc) * D + cd * 16 + (l & 15)] = f2b(o_acc[cd][r] * inv[r]);
        }
}

// ---------------------------------------------------------------------------
extern "C" void kernel_launch(void* const* d_in, const int* in_sizes, int n_in,
                              void* d_out, int out_size, void* d_ws, size_t ws_size,
                              hipStream_t stream) {
    const float* inputs  = (const float*)d_in[0];
    const float* ln_g    = (const float*)d_in[1];
    const float* ln_b    = (const float*)d_in[2];
    const float* Wq      = (const float*)d_in[3];
    const float* bq      = (const float*)d_in[4];
    const float* Wk      = (const float*)d_in[5];
    const float* bk      = (const float*)d_in[6];
    const float* Wv      = (const float*)d_in[7];
    const float* bv      = (const float*)d_in[8];
    const float* Wpos    = (const float*)d_in[9];
    const float* bpos    = (const float*)d_in[10];
    const float* Wo      = (const float*)d_in[11];
    const float* bo      = (const float*)d_in[12];
    const float* u_bias  = (const float*)d_in[13];
    const float* v_bias  = (const float*)d_in[14];
    float* out = (float*)d_out;

    char* w = (char*)d_ws;
    ush* xb   = (ush*)w;  w += (size_t)M_ROWS * D * 2;   // 4MB
    ush* qb   = (ush*)w;  w += (size_t)M_ROWS * D * 2;
    ush* kbuf = (ush*)w;  w += (size_t)M_ROWS * D * 2;
    ush* vtb  = (ush*)w;  w += (size_t)M_ROWS * D * 2;
    ush* ctxb = (ush*)w;  w += (size_t)M_ROWS * D * 2;
    ush* wb   = (ush*)w;  w += (size_t)4 * 65536 * 2;    // 512KB: Wq,Wk,Wv,Wo bf16
    float* posp = (float*)w; w += (size_t)NREL * D * 4;

    ln_kernel<<<M_ROWS / 4, 256, 0, stream>>>(inputs, ln_g, ln_b, xb);
    wconv<<<dim3(64, 4), 256, 0, stream>>>(Wq, Wk, Wv, Wo, wb);
    pos_kernel<<<NREL, 256, 0, stream>>>(Wpos, bpos, posp);

    dim3 pgrid(M_ROWS / 128, 2);
    proj_mfma<<<pgrid, 256, 0, stream>>>(xb, wb,             bq, qb,   nullptr, 0);
    proj_mfma<<<pgrid, 256, 0, stream>>>(xb, wb + 65536,     bk, kbuf, nullptr, 0);
    proj_mfma<<<pgrid, 256, 0, stream>>>(xb, wb + 2 * 65536, bv, vtb,  nullptr, 1);

    dim3 agrid(T / QBLK, B * H);
    attn_mfma<<<agrid, 256, 0, stream>>>(qb, kbuf, vtb, posp, u_bias, v_bias, ctxb);

    proj_mfma<<<pgrid, 256, 0, stream>>>(ctxb, wb + 3 * 65536, bo, nullptr, out, 2);
}

// Round 4
// 61.788 us; speedup vs baseline: 6.4873x; 1.2628x over previous
//
#include <hip/hip_runtime.h>
#include <hip/hip_bf16.h>
#include <math.h>

#define B 16
#define T 512
#define D 256
#define H 4
#define HD 64
#define MAXREL 30
#define NREL 61
#define M_ROWS (B*T)     // 8192
#define QBLK 64

typedef __attribute__((ext_vector_type(8))) short bf16x8;
typedef __attribute__((ext_vector_type(4))) float f32x4;
typedef unsigned short ush;

__device__ inline ush f2b(float f) {
    __hip_bfloat16 h = __float2bfloat16(f);
    union { __hip_bfloat16 h; ush u; } c; c.h = h; return c.u;
}
__device__ inline float b2f(ush u) {
    union { ush u; __hip_bfloat16 h; } c; c.u = u; return __bfloat162float(c.h);
}
// swizzled byte offset inside a [rows][64] bf16 tile (128B rows)
__device__ inline int swz(int row, int byteoff) {
    return row * 128 + (byteoff ^ ((row & 7) << 4));
}
// swizzled byte offset inside a [rows][128] bf16 tile (256B rows)
__device__ inline int swz256(int row, int byteoff) {
    return row * 256 + (byteoff ^ ((row & 7) << 4));
}

// ---------------------------------------------------------------------------
// prep: LN (blocks 0..2047) + weight bf16 conv (2048..2303) + pos table (2304..2364)
// ---------------------------------------------------------------------------
__global__ __launch_bounds__(256) void prep_kernel(const float* __restrict__ x,
                                                   const float* __restrict__ gamma,
                                                   const float* __restrict__ beta,
                                                   ush* __restrict__ xb,
                                                   const float* __restrict__ Wq, const float* __restrict__ Wk,
                                                   const float* __restrict__ Wv, const float* __restrict__ Wo,
                                                   ush* __restrict__ wb,
                                                   const float* __restrict__ Wpos,
                                                   const float* __restrict__ bpos,
                                                   float* __restrict__ posp) {
    int bid = blockIdx.x;
    int tid = threadIdx.x;
    if (bid < 2048) {
        int row = bid * 4 + (tid >> 6);
        int lane = tid & 63;
        const float* xr = x + (size_t)row * D;
        float4 v = *(const float4*)(xr + lane * 4);
        float s = v.x + v.y + v.z + v.w;
        #pragma unroll
        for (int off = 32; off; off >>= 1) s += __shfl_xor(s, off);
        float mu = s * (1.f / 256.f);
        float dx = v.x - mu, dy = v.y - mu, dz = v.z - mu, dw = v.w - mu;
        float vs = dx*dx + dy*dy + dz*dz + dw*dw;
        #pragma unroll
        for (int off = 32; off; off >>= 1) vs += __shfl_xor(vs, off);
        float rstd = rsqrtf(vs * (1.f / 256.f) + 1e-5f);
        float4 g = *(const float4*)(gamma + lane * 4);
        float4 bb = *(const float4*)(beta + lane * 4);
        ushort4 o;
        o.x = f2b(dx * rstd * g.x + bb.x);
        o.y = f2b(dy * rstd * g.y + bb.y);
        o.z = f2b(dz * rstd * g.z + bb.z);
        o.w = f2b(dw * rstd * g.w + bb.w);
        *(ushort4*)(xb + (size_t)row * D + lane * 4) = o;
    } else if (bid < 2048 + 256) {
        int b2 = bid - 2048;
        int z = b2 >> 6, xblk = b2 & 63;
        const float* src = z == 0 ? Wq : z == 1 ? Wk : z == 2 ? Wv : Wo;
        int idx = (xblk * 256 + tid) * 4;
        float4 v = *(const float4*)(src + idx);
        ushort4 o;
        o.x = f2b(v.x); o.y = f2b(v.y); o.z = f2b(v.z); o.w = f2b(v.w);
        *(ushort4*)(wb + (size_t)z * 65536 + idx) = o;
    } else {
        __shared__ float enc[256];
        int p = bid - 2304;
        int i = tid >> 1;
        float dt = expf(-(2.f * i) * (9.210340371976184f / 256.f));
        float ang = (float)p * dt;
        enc[tid] = (tid & 1) ? cosf(ang) : sinf(ang);
        __syncthreads();
        float acc = bpos[tid];
        const float* wr = Wpos + (size_t)tid * D;
        #pragma unroll 8
        for (int k2 = 0; k2 < 256; ++k2) acc += enc[k2] * wr[k2];
        posp[p * D + tid] = acc;
    }
}

// ---------------------------------------------------------------------------
// Shared MFMA GEMM core (128x128 tile, BK=128, 4 waves 2x2, swizzled LDS).
// swap=0: D[j][t] (quad = 4 consecutive j at fixed t). swap=1: D[t][j].
// ---------------------------------------------------------------------------
#define PROJ_CORE \
    f32x4 acc[4][4] = {}; \
    { const ush* Ap = A + (size_t)i0 * D; \
      const ush* Wp = W + (size_t)j0 * D; \
      _Pragma("unroll 1") \
      for (int kb2 = 0; kb2 < 2; ++kb2) { \
        int k0 = kb2 * 128; \
        if (kb2) __syncthreads(); \
        _Pragma("unroll") \
        for (int c = 0; c < 8; ++c) { \
            int ci = c * 256 + tid; \
            int row = ci >> 4, sub = ci & 15; \
            *(bf16x8*)((char*)A_s + swz256(row, sub * 16)) = *(const bf16x8*)(Ap + (size_t)row * D + k0 + sub * 8); \
            *(bf16x8*)((char*)B_s + swz256(row, sub * 16)) = *(const bf16x8*)(Wp + (size_t)row * D + k0 + sub * 8); \
        } \
        __syncthreads(); \
        const char* aSrc = swap ? (const char*)A_s : (const char*)B_s; \
        const char* bSrc = swap ? (const char*)B_s : (const char*)A_s; \
        __builtin_amdgcn_s_setprio(1); \
        _Pragma("unroll") \
        for (int ksub = 0; ksub < 4; ++ksub) { \
            int kbyte = ksub * 64 + (l >> 4) * 16; \
            bf16x8 af[4], bfr[4]; \
            _Pragma("unroll") \
            for (int mi = 0; mi < 4; ++mi) af[mi]  = *(const bf16x8*)(aSrc + swz256(wr * 64 + mi * 16 + (l & 15), kbyte)); \
            _Pragma("unroll") \
            for (int ni = 0; ni < 4; ++ni) bfr[ni] = *(const bf16x8*)(bSrc + swz256(wc * 64 + ni * 16 + (l & 15), kbyte)); \
            _Pragma("unroll") \
            for (int mi = 0; mi < 4; ++mi) \
                _Pragma("unroll") \
                for (int ni = 0; ni < 4; ++ni) \
                    acc[mi][ni] = __builtin_amdgcn_mfma_f32_16x16x32_bf16(af[mi], bfr[ni], acc[mi][ni], 0, 0, 0); \
        } \
        __builtin_amdgcn_s_setprio(0); \
      } }

// Fused QKV projection. grid (64, 2, 3): z=0 -> Q, z=1 -> K (row-major bf16),
// z=2 -> V^T (transposed bf16).
__global__ __launch_bounds__(256, 2) void qkv_mfma(const ush* __restrict__ A,
                                                   const ush* __restrict__ wball,
                                                   const float* __restrict__ bq,
                                                   const float* __restrict__ bk,
                                                   const float* __restrict__ bv,
                                                   ush* __restrict__ qb,
                                                   ush* __restrict__ kbuf,
                                                   ush* __restrict__ vtb) {
    __shared__ __attribute__((aligned(16))) ush A_s[128 * 128];
    __shared__ __attribute__((aligned(16))) ush B_s[128 * 128];
    int tid = threadIdx.x;
    int w = tid >> 6, l = tid & 63;
    int wr = w >> 1, wc = w & 1;
    int i0 = blockIdx.x * 128, j0 = blockIdx.y * 128;
    int z = blockIdx.z;
    const ush* W = wball + (size_t)z * 65536;
    const float* bias = z == 0 ? bq : (z == 1 ? bk : bv);
    int swap = (z == 2) ? 1 : 0;
    PROJ_CORE
    if (swap) {
        // D[t][j]: quad = 4 consecutive t at fixed j -> ushort4 into vtb[j][t]
        #pragma unroll
        for (int mi = 0; mi < 4; ++mi) {
            int t = i0 + wr * 64 + mi * 16 + (l >> 4) * 4;
            #pragma unroll
            for (int ni = 0; ni < 4; ++ni) {
                int j = j0 + wc * 64 + ni * 16 + (l & 15);
                float bvv = bias[j];
                ushort4 o;
                o.x = f2b(acc[mi][ni][0] + bvv); o.y = f2b(acc[mi][ni][1] + bvv);
                o.z = f2b(acc[mi][ni][2] + bvv); o.w = f2b(acc[mi][ni][3] + bvv);
                *(ushort4*)(vtb + (size_t)j * M_ROWS + t) = o;
            }
        }
    } else {
        ush* ob = (z == 0) ? qb : kbuf;
        #pragma unroll
        for (int mi = 0; mi < 4; ++mi) {
            int jb = j0 + wr * 64 + mi * 16 + (l >> 4) * 4;
            float4 bv4 = *(const float4*)(bias + jb);
            #pragma unroll
            for (int ni = 0; ni < 4; ++ni) {
                int t = i0 + wc * 64 + ni * 16 + (l & 15);
                ushort4 o;
                o.x = f2b(acc[mi][ni][0] + bv4.x); o.y = f2b(acc[mi][ni][1] + bv4.y);
                o.z = f2b(acc[mi][ni][2] + bv4.z); o.w = f2b(acc[mi][ni][3] + bv4.w);
                *(ushort4*)(ob + (size_t)t * D + jb) = o;
            }
        }
    }
}

// Out-projection: fp32 output.
__global__ __launch_bounds__(256, 2) void outproj_mfma(const ush* __restrict__ A,
                                                       const ush* __restrict__ W,
                                                       const float* __restrict__ bias,
                                                       float* __restrict__ of) {
    __shared__ __attribute__((aligned(16))) ush A_s[128 * 128];
    __shared__ __attribute__((aligned(16))) ush B_s[128 * 128];
    int tid = threadIdx.x;
    int w = tid >> 6, l = tid & 63;
    int wr = w >> 1, wc = w & 1;
    int i0 = blockIdx.x * 128, j0 = blockIdx.y * 128;
    const int swap = 0;
    PROJ_CORE
    #pragma unroll
    for (int mi = 0; mi < 4; ++mi) {
        int jb = j0 + wr * 64 + mi * 16 + (l >> 4) * 4;
        float4 bv4 = *(const float4*)(bias + jb);
        #pragma unroll
        for (int ni = 0; ni < 4; ++ni) {
            int t = i0 + wc * 64 + ni * 16 + (l & 15);
            float4 o;
            o.x = acc[mi][ni][0] + bv4.x; o.y = acc[mi][ni][1] + bv4.y;
            o.z = acc[mi][ni][2] + bv4.z; o.w = acc[mi][ni][3] + bv4.w;
            *(float4*)(of + (size_t)t * D + jb) = o;
        }
    }
}

// ---------------------------------------------------------------------------
// Flash MFMA attention. Block = (b,h) x 64 queries, 4 waves x 16 rows.
// Q in registers; K/V single-buffered LDS with async issue-early/write-late
// prefetch (T14); pd bf16 in LDS (stride 66); defer-max (T13).
// ---------------------------------------------------------------------------
__global__ __launch_bounds__(256, 4) void attn_mfma(const ush* __restrict__ qb,
                                                    const ush* __restrict__ kb,
                                                    const ush* __restrict__ vtb,
                                                    const float* __restrict__ posp,
                                                    const float* __restrict__ u_bias,
                                                    const float* __restrict__ v_bias,
                                                    ush* __restrict__ ctxb) {
    __shared__ __attribute__((aligned(16))) ush KbS[64 * 64];   // 8KB: posp, then K tiles
    __shared__ __attribute__((aligned(16))) ush VtS[64 * 64];   // 8KB
    __shared__ __attribute__((aligned(16))) ush pdS[64 * 66];   // 8.25KB bf16 [t_loc][rel], stride 66
    __shared__ __attribute__((aligned(16))) ush PlS[4][16 * 64];// 8KB

    int tid = threadIdx.x;
    int w = tid >> 6;
    int l = tid & 63;
    int bh = blockIdx.y;
    int b = bh >> 2, h = bh & 3;
    int t0 = blockIdx.x * QBLK;
    const size_t baseBH = ((size_t)b * T) * D + h * HD;

    // ---- Q fragments in registers (A-frag: row = l&15, k-chunk = (l>>4)*8), scaled by 1/8 ----
    bf16x8 qu[2], qv[2];
    {
        const ush* qrow = qb + baseBH + (size_t)(t0 + w * 16 + (l & 15)) * D;
        int c0 = (l >> 4) * 8;
        #pragma unroll
        for (int ks = 0; ks < 2; ++ks) {
            bf16x8 ld = *(const bf16x8*)(qrow + ks * 32 + c0);
            float4 ub0 = *(const float4*)(u_bias + h * HD + ks * 32 + c0);
            float4 ub1 = *(const float4*)(u_bias + h * HD + ks * 32 + c0 + 4);
            float4 vb0 = *(const float4*)(v_bias + h * HD + ks * 32 + c0);
            float4 vb1 = *(const float4*)(v_bias + h * HD + ks * 32 + c0 + 4);
            float ubv[8] = {ub0.x,ub0.y,ub0.z,ub0.w,ub1.x,ub1.y,ub1.z,ub1.w};
            float vbv[8] = {vb0.x,vb0.y,vb0.z,vb0.w,vb1.x,vb1.y,vb1.z,vb1.w};
            #pragma unroll
            for (int j = 0; j < 8; ++j) {
                float f = b2f((ush)ld[j]);
                qu[ks][j] = (short)f2b((f + ubv[j]) * 0.125f);
                qv[ks][j] = (short)f2b((f + vbv[j]) * 0.125f);
            }
        }
    }
    // ---- stage posp head-slice (bf16) into KbS (rows 61..63 zero) ----
    #pragma unroll
    for (int c = 0; c < 4; ++c) {
        int idx = tid + c * 256;
        int r = idx >> 4, d4 = (idx & 15) * 4;
        float4 pv = make_float4(0.f, 0.f, 0.f, 0.f);
        if (r < NREL) pv = *(const float4*)(posp + (size_t)r * D + h * HD + d4);
        ushort4 o;
        o.x = f2b(pv.x); o.y = f2b(pv.y); o.z = f2b(pv.z); o.w = f2b(pv.w);
        *(ushort4*)((char*)KbS + swz(r, d4 * 2)) = o;
    }
    __syncthreads();

    // ---- pd[t][rel] = (q/8 + v_bias/8) . posp_h  via MFMA -> bf16 LDS ----
    {
        f32x4 pacc[4] = {};
        #pragma unroll
        for (int ks = 0; ks < 2; ++ks) {
            #pragma unroll
            for (int ct = 0; ct < 4; ++ct) {
                bf16x8 bf = *(const bf16x8*)((const char*)KbS + swz(ct * 16 + (l & 15), (ks * 32 + (l >> 4) * 8) * 2));
                pacc[ct] = __builtin_amdgcn_mfma_f32_16x16x32_bf16(qv[ks], bf, pacc[ct], 0, 0, 0);
            }
        }
        #pragma unroll
        for (int ct = 0; ct < 4; ++ct)
            #pragma unroll
            for (int r = 0; r < 4; ++r)
                pdS[(w * 16 + (l >> 4) * 4 + r) * 66 + ct * 16 + (l & 15)] = f2b(pacc[ct][r]);
    }

    // staging indices (each thread handles 2 chunks of the 64x64 tile)
    int sr0 = tid >> 3,        sd0 = (tid & 7) * 8;
    int sr1 = (tid + 256) >> 3, sd1 = ((tid + 256) & 7) * 8;
    const ush* vsrc = vtb + (size_t)(h * HD) * M_ROWS + (size_t)b * T;
    const ush* ksrc = kb + baseBH;

    // ---- prefetch tile 0 into regs ----
    bf16x8 pk0, pk1, pv0, pv1;
    pk0 = *(const bf16x8*)(ksrc + (size_t)sr0 * D + sd0);
    pk1 = *(const bf16x8*)(ksrc + (size_t)sr1 * D + sd1);
    pv0 = *(const bf16x8*)(vsrc + (size_t)sr0 * M_ROWS + sd0);
    pv1 = *(const bf16x8*)(vsrc + (size_t)sr1 * M_ROWS + sd1);
    __syncthreads();   // pd MFMA done reading KbS
    *(bf16x8*)((char*)KbS + swz(sr0, sd0 * 2)) = pk0;
    *(bf16x8*)((char*)KbS + swz(sr1, sd1 * 2)) = pk1;
    *(bf16x8*)((char*)VtS + swz(sr0, sd0 * 2)) = pv0;
    *(bf16x8*)((char*)VtS + swz(sr1, sd1 * 2)) = pv1;
    __syncthreads();

    // ---- flash main loop ----
    float m_run[4] = {-1e30f, -1e30f, -1e30f, -1e30f};
    float l_run[4] = {};
    f32x4 o_acc[4] = {};

    for (int st = 0; st < 8; ++st) {
        int s0 = st * 64;
        // issue next tile's global loads early (overlap with compute)
        if (st < 7) {
            int sn = s0 + 64;
            pk0 = *(const bf16x8*)(ksrc + (size_t)(sn + sr0) * D + sd0);
            pk1 = *(const bf16x8*)(ksrc + (size_t)(sn + sr1) * D + sd1);
            pv0 = *(const bf16x8*)(vsrc + (size_t)sr0 * M_ROWS + sn + sd0);
            pv1 = *(const bf16x8*)(vsrc + (size_t)sr1 * M_ROWS + sn + sd1);
        }

        // QK^T (pre-scaled by 1/8 via qu)
        f32x4 sacc[4] = {};
        __builtin_amdgcn_s_setprio(1);
        #pragma unroll
        for (int ks = 0; ks < 2; ++ks) {
            #pragma unroll
            for (int ct = 0; ct < 4; ++ct) {
                bf16x8 bf = *(const bf16x8*)((const char*)KbS + swz(ct * 16 + (l & 15), (ks * 32 + (l >> 4) * 8) * 2));
                sacc[ct] = __builtin_amdgcn_mfma_f32_16x16x32_bf16(qu[ks], bf, sacc[ct], 0, 0, 0);
            }
        }
        __builtin_amdgcn_s_setprio(0);

        // + pos term (pre-scaled, bf16 gather)
        #pragma unroll
        for (int ct = 0; ct < 4; ++ct) {
            int s_g = s0 + ct * 16 + (l & 15);
            #pragma unroll
            for (int r = 0; r < 4; ++r) {
                int t_loc = w * 16 + (l >> 4) * 4 + r;
                int rel = s_g - (t0 + t_loc);
                rel = rel < -MAXREL ? -MAXREL : (rel > MAXREL ? MAXREL : rel);
                sacc[ct][r] += b2f(pdS[t_loc * 66 + rel + MAXREL]);
            }
        }

        // online softmax with defer-max (THR=8)
        float mt[4];
        float need = 0.f;
        #pragma unroll
        for (int r = 0; r < 4; ++r) {
            float m4 = fmaxf(fmaxf(sacc[0][r], sacc[1][r]), fmaxf(sacc[2][r], sacc[3][r]));
            #pragma unroll
            for (int off = 8; off; off >>= 1) m4 = fmaxf(m4, __shfl_xor(m4, off));
            mt[r] = m4;
            need = fmaxf(need, m4 - m_run[r]);
        }
        if (__any(need > 8.f)) {
            #pragma unroll
            for (int r = 0; r < 4; ++r) {
                float mn = fmaxf(m_run[r], mt[r]);
                float al = __expf(m_run[r] - mn);
                m_run[r] = mn;
                l_run[r] *= al;
                #pragma unroll
                for (int cd = 0; cd < 4; ++cd) o_acc[cd][r] *= al;
            }
        }
        #pragma unroll
        for (int r = 0; r < 4; ++r) {
            float rs = 0.f;
            #pragma unroll
            for (int ct = 0; ct < 4; ++ct) {
                float p = __expf(sacc[ct][r] - m_run[r]);
                sacc[ct][r] = p;
                rs += p;
            }
            #pragma unroll
            for (int off = 8; off; off >>= 1) rs += __shfl_xor(rs, off);
            l_run[r] += rs;
        }

        // P -> bf16 LDS (per-wave region)
        ush* pw = PlS[w];
        #pragma unroll
        for (int ct = 0; ct < 4; ++ct)
            #pragma unroll
            for (int r = 0; r < 4; ++r) {
                int row = (l >> 4) * 4 + r;
                int col = ct * 16 + (l & 15);
                *(ush*)((char*)pw + swz(row, col * 2)) = f2b(sacc[ct][r]);
            }

        // PV
        __builtin_amdgcn_s_setprio(1);
        #pragma unroll
        for (int ks = 0; ks < 2; ++ks) {
            bf16x8 a = *(const bf16x8*)((const char*)pw + swz(l & 15, (ks * 32 + (l >> 4) * 8) * 2));
            #pragma unroll
            for (int cd = 0; cd < 4; ++cd) {
                bf16x8 bv8 = *(const bf16x8*)((const char*)VtS + swz(cd * 16 + (l & 15), (ks * 32 + (l >> 4) * 8) * 2));
                o_acc[cd] = __builtin_amdgcn_mfma_f32_16x16x32_bf16(a, bv8, o_acc[cd], 0, 0, 0);
            }
        }
        __builtin_amdgcn_s_setprio(0);

        // write-late: commit prefetched tile to LDS
        if (st < 7) {
            __syncthreads();   // all waves done reading KbS/VtS
            *(bf16x8*)((char*)KbS + swz(sr0, sd0 * 2)) = pk0;
            *(bf16x8*)((char*)KbS + swz(sr1, sd1 * 2)) = pk1;
            *(bf16x8*)((char*)VtS + swz(sr0, sd0 * 2)) = pv0;
            *(bf16x8*)((char*)VtS + swz(sr1, sd1 * 2)) = pv1;
            __syncthreads();
        }
    }

    // ---- normalize + write ctx (bf16 row-major) ----
    float inv[4];
    #pragma unroll
    for (int r = 0; r < 4; ++r) inv[r] = 1.f / l_run[r];
    #pragma unroll
    for (int cd = 0; cd < 4; ++cd)
        #pragma unroll
        for (int r = 0; r < 4; ++r) {
            int t_loc = w * 16 + (l >> 4) * 4 + r;
            ctxb[baseBH + (size_t)(t0 + t_loc) * D + cd * 16 + (l & 15)] = f2b(o_acc[cd][r] * inv[r]);
        }
}

// ---------------------------------------------------------------------------
extern "C" void kernel_launch(void* const* d_in, const int* in_sizes, int n_in,
                              void* d_out, int out_size, void* d_ws, size_t ws_size,
                              hipStream_t stream) {
    const float* inputs  = (const float*)d_in[0];
    const float* ln_g    = (const float*)d_in[1];
    const float* ln_b    = (const float*)d_in[2];
    const float* Wq      = (const float*)d_in[3];
    const float* bq      = (const float*)d_in[4];
    const float* Wk      = (const float*)d_in[5];
    const float* bk      = (const float*)d_in[6];
    const float* Wv      = (const float*)d_in[7];
    const float* bv      = (const float*)d_in[8];
    const float* Wpos    = (const float*)d_in[9];
    const float* bpos    = (const float*)d_in[10];
    const float* Wo      = (const float*)d_in[11];
    const float* bo      = (const float*)d_in[12];
    const float* u_bias  = (const float*)d_in[13];
    const float* v_bias  = (const float*)d_in[14];
    float* out = (float*)d_out;

    char* w = (char*)d_ws;
    ush* xb   = (ush*)w;  w += (size_t)M_ROWS * D * 2;   // 4MB
    ush* qb   = (ush*)w;  w += (size_t)M_ROWS * D * 2;
    ush* kbuf = (ush*)w;  w += (size_t)M_ROWS * D * 2;
    ush* vtb  = (ush*)w;  w += (size_t)M_ROWS * D * 2;
    ush* ctxb = (ush*)w;  w += (size_t)M_ROWS * D * 2;
    ush* wb   = (ush*)w;  w += (size_t)4 * 65536 * 2;    // 512KB
    float* posp = (float*)w; w += (size_t)NREL * D * 4;

    prep_kernel<<<2048 + 256 + NREL, 256, 0, stream>>>(inputs, ln_g, ln_b, xb,
                                                       Wq, Wk, Wv, Wo, wb,
                                                       Wpos, bpos, posp);

    qkv_mfma<<<dim3(M_ROWS / 128, 2, 3), 256, 0, stream>>>(xb, wb, bq, bk, bv, qb, kbuf, vtb);

    attn_mfma<<<dim3(T / QBLK, B * H), 256, 0, stream>>>(qb, kbuf, vtb, posp, u_bias, v_bias, ctxb);

    outproj_mfma<<<dim3(M_ROWS / 128, 2), 256, 0, stream>>>(ctxb, wb + 3 * 65536, bo, out);
}